// Round 1
// baseline (2900.775 us; speedup 1.0000x reference)
//
#include <hip/hip_runtime.h>
#include <math.h>

#define WDIM 256
#define HW   65536

struct cplx { float x, y; };
__device__ __forceinline__ cplx cmul(cplx a, cplx b){ return {a.x*b.x - a.y*b.y, a.x*b.y + a.y*b.x}; }
__device__ __forceinline__ cplx cadd(cplx a, cplx b){ return {a.x+b.x, a.y+b.y}; }
__device__ __forceinline__ cplx csub(cplx a, cplx b){ return {a.x-b.x, a.y-b.y}; }
__device__ __forceinline__ void swapc(cplx& a, cplx& b){ cplx t=a; a=b; b=t; }

// ---------------- 16-point FFT in registers (radix-2 DIT, bit-reversed input) ----
template<bool INV>
__device__ __forceinline__ void fft16(cplx v[16]) {
  const float C16[8] = {1.f, 0.9238795325112867f, 0.7071067811865476f, 0.3826834323650898f,
                        0.f, -0.3826834323650898f, -0.7071067811865476f, -0.9238795325112867f};
  const float S16[8] = {0.f, 0.3826834323650898f, 0.7071067811865476f, 0.9238795325112867f,
                        1.f, 0.9238795325112867f, 0.7071067811865476f, 0.3826834323650898f};
  swapc(v[1], v[8]); swapc(v[2], v[4]); swapc(v[3], v[12]);
  swapc(v[5], v[10]); swapc(v[7], v[14]); swapc(v[11], v[13]);
  #pragma unroll
  for (int s = 1; s <= 4; ++s) {
    const int m = 1 << s, half = m >> 1, step = 16 >> s;
    #pragma unroll
    for (int k = 0; k < 16; k += m) {
      #pragma unroll
      for (int j = 0; j < half; ++j) {
        cplx w = {C16[j*step], INV ? S16[j*step] : -S16[j*step]};
        cplx t = cmul(w, v[k+j+half]);
        v[k+j+half] = csub(v[k+j], t);
        v[k+j]      = cadd(v[k+j], t);
      }
    }
  }
}

// 256-pt FFT: 16 threads (t=0..15) per FFT; thread t holds x[16a+t] (a=0..15) on
// entry, X[t+16d] (d=0..15) on exit. Yu = per-unit LDS region (16*17 cplx, may
// alias caller LDS; internal barriers fence it).
template<bool INV>
__device__ void fft256_16(cplx v[16], int t, cplx* Yu) {
  fft16<INV>(v);
  float ang = (INV ? 6.283185307179586f : -6.283185307179586f) * (float)t * (1.0f/256.0f);
  float sn, cs; sincosf(ang, &sn, &cs);
  cplx wstep = {cs, sn}, w = {1.f, 0.f};
  #pragma unroll
  for (int c = 0; c < 16; ++c) { v[c] = cmul(v[c], w); w = cmul(w, wstep); }
  __syncthreads();                       // all prior LDS reads complete (Yu may alias)
  #pragma unroll
  for (int c = 0; c < 16; ++c) Yu[t*17 + c] = v[c];
  __syncthreads();
  cplx z[16];
  #pragma unroll
  for (int b = 0; b < 16; ++b) z[b] = Yu[b*17 + t];
  fft16<INV>(z);
  #pragma unroll
  for (int d = 0; d < 16; ++d) v[d] = z[d];
  __syncthreads();                       // caller may reuse LDS
}

// ---------------- row FFT kernels (grid: (16 rowgroups, planes), 256 thr) -------
__global__ __launch_bounds__(256) void k_row_fwd_sub(const float* __restrict__ a,
                                                     const float* __restrict__ b,
                                                     cplx* __restrict__ out) {
  __shared__ cplx Y[16*280];
  int unit = threadIdx.x >> 4, t = threadIdx.x & 15;
  size_t base = (size_t)blockIdx.y*HW + (size_t)(blockIdx.x*16 + unit)*WDIM;
  cplx v[16];
  #pragma unroll
  for (int i = 0; i < 16; ++i) { size_t idx = base + i*16 + t; v[i] = {a[idx] - b[idx], 0.f}; }
  fft256_16<false>(v, t, Y + unit*280);
  #pragma unroll
  for (int d = 0; d < 16; ++d) out[base + t + 16*d] = v[d];
}

__global__ __launch_bounds__(256) void k_row_inv(const cplx* __restrict__ in,
                                                 cplx* __restrict__ out) {
  __shared__ cplx Y[16*280];
  int unit = threadIdx.x >> 4, t = threadIdx.x & 15;
  size_t base = (size_t)blockIdx.y*HW + (size_t)(blockIdx.x*16 + unit)*WDIM;
  cplx v[16];
  #pragma unroll
  for (int i = 0; i < 16; ++i) v[i] = in[base + i*16 + t];
  fft256_16<true>(v, t, Y + unit*280);
  #pragma unroll
  for (int d = 0; d < 16; ++d) out[base + t + 16*d] = {v[d].x*(1.f/256.f), v[d].y*(1.f/256.f)};
}

// ---------------- column FFT core (grid: (16 col-tiles, planes), 256 thr) -------
// Loads a 256(h) x 16(w) tile coalesced into LDS, FFTs each column (one 16-thread
// unit per column). On return thread (u=tid>>4 col, t=tid&15) holds X[t+16d].
template<bool INV>
__device__ void col_core(const cplx* __restrict__ in, cplx* lds, cplx v[16], size_t planeBase) {
  int tid = threadIdx.x;
  #pragma unroll
  for (int i = 0; i < 16; ++i) {
    int idx = tid + 256*i; int h = idx >> 4, w = idx & 15;
    lds[h*17 + w] = in[planeBase + (size_t)h*WDIM + w];
  }
  __syncthreads();
  int u = tid >> 4, t = tid & 15;
  cplx vv[16];
  #pragma unroll
  for (int a = 0; a < 16; ++a) vv[a] = lds[(16*a + t)*17 + u];
  fft256_16<INV>(vv, t, lds + u*280);
  #pragma unroll
  for (int d = 0; d < 16; ++d) v[d] = vv[d];
}

__global__ __launch_bounds__(256) void k_col_fwd(cplx* __restrict__ buf) {
  __shared__ cplx lds[4480];
  size_t planeBase = (size_t)blockIdx.y*HW + blockIdx.x*16;
  cplx v[16];
  col_core<false>(buf, lds, v, planeBase);
  int u = threadIdx.x >> 4, t = threadIdx.x & 15;
  #pragma unroll
  for (int d = 0; d < 16; ++d) lds[(t + 16*d)*17 + u] = v[d];
  __syncthreads();
  int tid = threadIdx.x;
  #pragma unroll
  for (int i = 0; i < 16; ++i) {
    int idx = tid + 256*i; int h = idx >> 4, w = idx & 15;
    buf[planeBase + (size_t)h*WDIM + w] = lds[h*17 + w];
  }
}

// inverse cols -> real x and z_tilde = x + u2
__global__ __launch_bounds__(256) void k_col_inv_real_zt(const cplx* __restrict__ in,
                                                         const float* __restrict__ u2,
                                                         float* __restrict__ xout,
                                                         float* __restrict__ zt) {
  __shared__ cplx lds[4480];
  float* ldsf = (float*)lds;
  size_t planeBase = (size_t)blockIdx.y*HW + blockIdx.x*16;
  cplx v[16];
  col_core<true>(in, lds, v, planeBase);
  int u = threadIdx.x >> 4, t = threadIdx.x & 15;
  #pragma unroll
  for (int d = 0; d < 16; ++d) ldsf[(t + 16*d)*17 + u] = v[d].x * (1.f/256.f);
  __syncthreads();
  int tid = threadIdx.x;
  #pragma unroll
  for (int i = 0; i < 16; ++i) {
    int idx = tid + 256*i; int h = idx >> 4, w = idx & 15;
    size_t g = planeBase + (size_t)h*WDIM + w;
    float val = ldsf[h*17 + w];
    xout[g] = val;
    zt[g]   = val + u2[g];
  }
}

// inverse cols -> |.| (holo) + per-block min/max partials
__global__ __launch_bounds__(256) void k_col_inv_abs(const cplx* __restrict__ in,
                                                     float* __restrict__ holo,
                                                     float* __restrict__ partials) {
  __shared__ cplx lds[4480];
  float* ldsf = (float*)lds;
  size_t planeBase = (size_t)blockIdx.y*HW + blockIdx.x*16;
  cplx v[16];
  col_core<true>(in, lds, v, planeBase);
  int u = threadIdx.x >> 4, t = threadIdx.x & 15;
  #pragma unroll
  for (int d = 0; d < 16; ++d) {
    float re = v[d].x*(1.f/256.f), im = v[d].y*(1.f/256.f);
    ldsf[(t + 16*d)*17 + u] = sqrtf(re*re + im*im);
  }
  __syncthreads();
  int tid = threadIdx.x;
  float mn = 1e30f, mx = -1e30f;
  #pragma unroll
  for (int i = 0; i < 16; ++i) {
    int idx = tid + 256*i; int h = idx >> 4, w = idx & 15;
    float val = ldsf[h*17 + w];
    holo[planeBase + (size_t)h*WDIM + w] = val;
    mn = fminf(mn, val); mx = fmaxf(mx, val);
  }
  __syncthreads();                              // all ldsf reads done before reuse
  #pragma unroll
  for (int s = 1; s < 64; s <<= 1) { mn = fminf(mn, __shfl_xor(mn, s)); mx = fmaxf(mx, __shfl_xor(mx, s)); }
  if ((tid & 63) == 0) { ldsf[(tid>>6)*2] = mn; ldsf[(tid>>6)*2 + 1] = mx; }
  __syncthreads();
  if (tid == 0) {
    float a = fminf(fminf(ldsf[0], ldsf[2]), fminf(ldsf[4], ldsf[6]));
    float b = fmaxf(fmaxf(ldsf[1], ldsf[3]), fmaxf(ldsf[5], ldsf[7]));
    partials[(blockIdx.y*16 + blockIdx.x)*2]     = a;
    partials[(blockIdx.y*16 + blockIdx.x)*2 + 1] = b;
  }
}

__global__ __launch_bounds__(64) void k_mm_reduce(const float* __restrict__ partials,
                                                  float* __restrict__ minmax) {
  int t = threadIdx.x; int b = t >> 4, i = t & 15;
  float mn = partials[(b*16 + i)*2], mx = partials[(b*16 + i)*2 + 1];
  #pragma unroll
  for (int s = 1; s < 16; s <<= 1) { mn = fminf(mn, __shfl_xor(mn, s)); mx = fmaxf(mx, __shfl_xor(mx, s)); }
  if (i == 0) { minmax[b*2] = mn; minmax[b*2 + 1] = mx; }
}

// ---------------- Fourier-domain combine: X_f = (rho1*herm(X1F*conj(otf)) + rho2*Z2F)/den
__global__ __launch_bounds__(256) void k_combine(cplx* __restrict__ W1,
                                                 const cplx* __restrict__ X1F,
                                                 const float* __restrict__ otr,
                                                 const float* __restrict__ oti,
                                                 const float* __restrict__ r1p,
                                                 const float* __restrict__ r2p) {
  int i = blockIdx.x*256 + threadIdx.x;               // [B,D,H,W]
  int kw = i & 255, kh = (i >> 8) & 255, bd = i >> 16, b = bd >> 5;
  int kh2 = (256 - kh) & 255, kw2 = (256 - kw) & 255;
  int i2 = (bd << 16) | (kh2 << 8) | kw2;
  int p  = (b << 16) | (kh << 8) | kw;
  int p2 = (b << 16) | (kh2 << 8) | kw2;
  cplx A = X1F[p], Am = X1F[p2];
  float or1 = otr[i], oi1 = oti[i], or2 = otr[i2], oi2 = oti[i2];
  // herm(G)[k] = 0.5*( X1F[k]*conj(otf[k]) + conj(X1F[-k])*otf[-k] )
  float hr = 0.5f*(A.x*or1 + A.y*oi1 + Am.x*or2 + Am.y*oi2);
  float hi = 0.5f*(A.y*or1 - A.x*oi1 + Am.x*oi2 - Am.y*or2);
  cplx z2 = W1[i];
  float rho1 = r1p[0], rho2 = r2p[0];
  float den = 1.0f / (rho2 + rho1*(or1*or1 + oi1*oi1));
  W1[i] = {(rho1*hr + rho2*z2.x)*den, (rho1*hi + rho2*z2.y)*den};
}

// ---------------- HF[b,k] = sum_d herm(XF)[b,d,k] * otf[b,d,k]
__global__ __launch_bounds__(256) void k_hf(const cplx* __restrict__ XF,
                                            const float* __restrict__ otr,
                                            const float* __restrict__ oti,
                                            cplx* __restrict__ HF) {
  int j = blockIdx.x*256 + threadIdx.x;               // [B,H,W]
  int b = j >> 16, kh = (j >> 8) & 255, kw = j & 255;
  int kh2 = (256 - kh) & 255, kw2 = (256 - kw) & 255;
  float ar = 0.f, ai = 0.f;
  for (int d = 0; d < 32; ++d) {
    int base = ((b*32 + d) << 16);
    int idx  = base | (kh << 8) | kw;
    int idx2 = base | (kh2 << 8) | kw2;
    cplx Xk = XF[idx], Xm = XF[idx2];
    float xr = 0.5f*(Xk.x + Xm.x), xi = 0.5f*(Xk.y - Xm.y);
    float o_r = otr[idx], o_i = oti[idx];
    ar += xr*o_r - xi*o_i;
    ai += xr*o_i + xi*o_r;
  }
  HF[j] = {ar, ai};
}

// ---------------- Phi update: min-max scale + 30-step masked bisection ----------
__global__ __launch_bounds__(256) void k_bisect(const float* __restrict__ holo,
                                                const float* __restrict__ minmax,
                                                const float* __restrict__ u1,
                                                const int* __restrict__ K1,
                                                const float* __restrict__ r1p,
                                                float* __restrict__ phi_out,
                                                float* __restrict__ u1_out) {
  int i = blockIdx.x*256 + threadIdx.x;               // [B,1,H,W]
  int b = i >> 16;
  float mn = minmax[2*b], mx = minmax[2*b + 1];
  float fp = (holo[i] - mn) / (mx - mn);
  float pt = fp + u1[i];
  float K1f = (float)K1[i];
  float K0 = 1.f - K1f;
  float rho1 = r1p[0];
  bool ind0i = (K1f == 0.f);
  bool ind0 = ind0i;
  float pmin = 1e-5f, pmax = 100.f, pave = 0.5f*(pmin + pmax);
  #pragma unroll 1
  for (int it = 0; it < 30; ++it) {                   // c = ALPHA/KFRAMES = 1
    float e = expf(pave);
    float t = (K0 - K1f/(e - 1.f)) + rho1*(pave - pt);
    bool ind1 = !ind0;
    if (t > 0.f && ind1) pmin = pave;
    if (t < 0.f && ind1) pmax = pave;
    ind0 = ind0 || (t == 0.f && ind1);
    if (!ind0) pave = 0.5f*(pmin + pmax);
  }
  float pn = ind0i ? (pt - K0/rho1) : pave;
  phi_out[i] = pn;
  u1_out[i]  = u1[i] + pn - fp;
}

// ---------------- direct 3x3 conv, 32->32, SAME, fused input transform + BN stats
// grid (W/64, H/8, B); 256 thr: ocl=tid>>6 (8 oc each), wl=tid&63.
// mode: 0 none, 1 BN(sc,sh)+leakyReLU, 2 soft-threshold(thr)
__global__ __launch_bounds__(256) void k_conv(const float* __restrict__ in,
                                              const float* __restrict__ wgt,
                                              float* __restrict__ out,
                                              float* __restrict__ stats,
                                              int mode,
                                              const float* __restrict__ sc,
                                              const float* __restrict__ sh,
                                              const float* __restrict__ thrp) {
  __shared__ __align__(16) float wlds[32*32*12];      // [ic][oc][12] (9 used)
  __shared__ float ilds[32*3*66];                     // [ic][3 rows][66]
  int tid = threadIdx.x;
  int ocl = tid >> 6, wl = tid & 63;
  int w0 = blockIdx.x * 64;
  int h0 = blockIdx.y * 8;
  int bz = blockIdx.z;
  float thr = (mode == 2) ? thrp[0] : 0.f;
  for (int idx = tid; idx < 32*32*9; idx += 256) {
    int oc = idx / 288, r = idx % 288, ic = r / 9, tap = r % 9;
    wlds[(ic*32 + oc)*12 + tap] = wgt[idx];
  }
  float ts[8], tss[8];
  #pragma unroll
  for (int q = 0; q < 8; ++q) { ts[q] = 0.f; tss[q] = 0.f; }

  for (int hh = 0; hh < 8; ++hh) {
    int h = h0 + hh;
    for (int idx = tid; idx < 32*3*66; idx += 256) {
      int ic = idx / 198, r = idx % 198, dy = r / 66, wq = r % 66;
      int gh = h - 1 + dy, gw = w0 - 1 + wq;
      float val = 0.f;
      if (gh >= 0 && gh < 256 && gw >= 0 && gw < 256) {
        val = in[(((size_t)bz*32 + ic)*256 + gh)*256 + gw];
        if (mode == 1) { val = val*sc[ic] + sh[ic]; val = (val > 0.f) ? val : 0.01f*val; }
        else if (mode == 2) { float s = fabsf(val) - thr; s = (s > 0.f) ? s : 0.f; val = copysignf(s, val); }
      }
      ilds[idx] = val;
    }
    __syncthreads();
    float acc[8];
    #pragma unroll
    for (int q = 0; q < 8; ++q) acc[q] = 0.f;
    for (int ic = 0; ic < 32; ++ic) {
      float iv[9];
      #pragma unroll
      for (int dy = 0; dy < 3; ++dy)
        #pragma unroll
        for (int dx = 0; dx < 3; ++dx)
          iv[dy*3 + dx] = ilds[ic*198 + dy*66 + wl + dx];
      #pragma unroll
      for (int q = 0; q < 8; ++q) {
        int oc = ocl*8 + q;
        const float* wp = &wlds[(ic*32 + oc)*12];
        float4 wa = *(const float4*)wp;
        float4 wb = *(const float4*)(wp + 4);
        float wc = wp[8];
        acc[q] += iv[0]*wa.x + iv[1]*wa.y + iv[2]*wa.z
                + iv[3]*wa.w + iv[4]*wb.x + iv[5]*wb.y
                + iv[6]*wb.z + iv[7]*wb.w + iv[8]*wc;
      }
    }
    #pragma unroll
    for (int q = 0; q < 8; ++q) {
      int oc = ocl*8 + q;
      size_t g = (((size_t)bz*32 + oc)*256 + h)*256 + w0 + wl;
      out[g] = acc[q];
      ts[q] += acc[q]; tss[q] += acc[q]*acc[q];
    }
    __syncthreads();
  }
  #pragma unroll
  for (int q = 0; q < 8; ++q) {
    float s = ts[q], s2 = tss[q];
    #pragma unroll
    for (int m = 1; m < 64; m <<= 1) { s += __shfl_xor(s, m); s2 += __shfl_xor(s2, m); }
    if (wl == 0) {
      int oc = ocl*8 + q;
      atomicAdd(&stats[oc], s);
      atomicAdd(&stats[32 + oc], s2);
    }
  }
}

__global__ __launch_bounds__(64) void k_finstats(const float* __restrict__ stats,
                                                 const float* __restrict__ g,
                                                 const float* __restrict__ bta,
                                                 float* __restrict__ scsh) {
  int t = threadIdx.x;
  if (t < 32) {
    const float N = 262144.f;                         // B*H*W
    float mean = stats[t] / N;
    float var  = stats[32 + t] / N - mean*mean;
    float s = g[t] * rsqrtf(var + 1e-5f);
    scsh[t] = s;
    scsh[32 + t] = bta[t] - mean*s;
  }
}

// ---------------- elementwise resblock finals ----------------------------------
__global__ __launch_bounds__(256) void k_h1(const float* __restrict__ zt,
                                            const float* __restrict__ bb,
                                            const float* __restrict__ scsh,
                                            float* __restrict__ h1) {
  int i = blockIdx.x*256 + threadIdx.x;
  int c = (i >> 16) & 31;
  float v = zt[i] + bb[i]*scsh[c] + scsh[32 + c];
  h1[i] = (v > 0.f) ? v : 0.01f*v;
}

__global__ __launch_bounds__(256) void k_znext(const float* __restrict__ h1,
                                               const float* __restrict__ bb,
                                               const float* __restrict__ scsh,
                                               const float* __restrict__ thrp,
                                               const float* __restrict__ u2,
                                               const float* __restrict__ x,
                                               float* __restrict__ zout,
                                               float* __restrict__ u2out) {
  int i = blockIdx.x*256 + threadIdx.x;
  int c = (i >> 16) & 31;
  float thr = thrp[0];
  float hv = h1[i];
  float s = fabsf(hv) - thr; s = (s > 0.f) ? s : 0.f;
  float th = copysignf(s, hv);
  float v = th + bb[i]*scsh[c] + scsh[32 + c];
  float z = (v > 0.f) ? v : 0.01f*v;
  zout[i]  = z;
  u2out[i] = u2[i] + z - x[i];
}

__global__ __launch_bounds__(256) void k_sym(const float* __restrict__ h1,
                                             const float* __restrict__ bb,
                                             const float* __restrict__ scsh,
                                             const float* __restrict__ zt,
                                             float* __restrict__ sym) {
  int i = blockIdx.x*256 + threadIdx.x;
  int c = (i >> 16) & 31;
  float v = h1[i] + bb[i]*scsh[c] + scsh[32 + c];
  float xfb = (v > 0.f) ? v : 0.01f*v;
  sym[i] = xfb - zt[i];
}

// ================================================================================
extern "C" void kernel_launch(void* const* d_in, const int* in_sizes, int n_in,
                              void* d_out, int out_size, void* d_ws, size_t ws_size,
                              hipStream_t stream) {
  const float* phi  = (const float*)d_in[1];
  const float* z    = (const float*)d_in[2];
  const float* u1   = (const float*)d_in[3];
  const float* u2   = (const float*)d_in[4];
  const float* otr  = (const float*)d_in[5];
  const float* oti  = (const float*)d_in[6];
  const int*   K1   = (const int*)d_in[7];
  const float* rho1 = (const float*)d_in[8];
  const float* rho2 = (const float*)d_in[9];
  const float* sthr = (const float*)d_in[10];
  const float* w1a = (const float*)d_in[11];
  const float* g1a = (const float*)d_in[12];
  const float* b1a = (const float*)d_in[13];
  const float* w1b = (const float*)d_in[14];
  const float* g1b = (const float*)d_in[15];
  const float* b1b = (const float*)d_in[16];
  const float* w2a = (const float*)d_in[17];
  const float* g2a = (const float*)d_in[18];
  const float* b2a = (const float*)d_in[19];
  const float* w2b = (const float*)d_in[20];
  const float* g2b = (const float*)d_in[21];
  const float* b2b = (const float*)d_in[22];

  float* out = (float*)d_out;
  float* x_out   = out;                 // [B,D,H,W] 8388608
  float* phi_out = out + 8388608;       // [B,1,H,W]  262144
  float* z_out   = out + 8650752;       // [B,D,H,W] 8388608
  float* u1_out  = out + 17039360;      // [B,1,H,W]  262144
  float* u2_out  = out + 17301504;      // [B,D,H,W] 8388608
  float* sym_out = out + 25690112;      // [B,D,H,W] 8388608

  // ws layout (~72.4 MB):
  char* ws = (char*)d_ws;
  cplx*  W1    = (cplx*)ws;                          // 67108864 B: Z2F -> XF; later ZT/H1
  cplx*  X1R   = (cplx*)(ws + 67108864);             // 2 MB: X1F, then HF
  cplx*  HFT   = (cplx*)(ws + 69206016);             // 2 MB
  float* holo  = (float*)(ws + 71303168);            // 1 MB
  float* part  = (float*)(ws + 72351744);
  float* mm    = (float*)(ws + 72355840);
  float* S     = (float*)(ws + 72359936);            // 6*64 stats
  float* SS    = (float*)(ws + 72364032);            // 6*64 scale/shift
  float* ZT = (float*)ws;                            // reuses W1 lower half
  float* H1 = (float*)(ws + 33554432);               // reuses W1 upper half
  // W2 (iFFT intermediate, [B,D] complex) lives in d_out: planes 0..63 in z_out
  // region, planes 64..127 in sym_out region (both dead until much later).
  cplx* W2lo = (cplx*)z_out;
  cplx* W2hi = (cplx*)sym_out;
  // conv temporaries in d_out dead zones:
  float* Abuf = z_out;                               // conv temp A (dead before k_znext)
  float* Bb   = u2_out;                              // c2/c4 out (k_znext reads+overwrites in place)
  float* Bb6  = sym_out;                             // c6 out (k_sym in place)

  hipMemsetAsync(S, 0, 6*64*sizeof(float), stream);

  // ---- X update (Fourier domain) ----
  k_row_fwd_sub<<<dim3(16, 4),   256, 0, stream>>>(phi, u1, X1R);
  k_col_fwd    <<<dim3(16, 4),   256, 0, stream>>>(X1R);
  k_row_fwd_sub<<<dim3(16, 128), 256, 0, stream>>>(z, u2, W1);
  k_col_fwd    <<<dim3(16, 128), 256, 0, stream>>>(W1);
  k_combine    <<<32768, 256, 0, stream>>>(W1, X1R, otr, oti, rho1, rho2);
  // forward_proj via Hermitian part of XF (no forward FFT needed)
  k_hf         <<<1024, 256, 0, stream>>>(W1, otr, oti, X1R /* = HF */);
  k_row_inv    <<<dim3(16, 4),   256, 0, stream>>>(X1R, HFT);
  k_col_inv_abs<<<dim3(16, 4),   256, 0, stream>>>(HFT, holo, part);
  k_mm_reduce  <<<1, 64, 0, stream>>>(part, mm);
  // x = Re(iFT(XF)), z_tilde = x + u2
  k_row_inv    <<<dim3(16, 64), 256, 0, stream>>>(W1, W2lo);
  k_row_inv    <<<dim3(16, 64), 256, 0, stream>>>(W1 + (size_t)64*HW, W2hi);
  k_col_inv_real_zt<<<dim3(16, 64), 256, 0, stream>>>(W2lo, u2, x_out, ZT);
  k_col_inv_real_zt<<<dim3(16, 64), 256, 0, stream>>>(W2hi, u2 + (size_t)64*HW,
                                                      x_out + (size_t)64*HW, ZT + (size_t)64*HW);
  // ---- Phi update ----
  k_bisect<<<1024, 256, 0, stream>>>(holo, mm, u1, K1, rho1, phi_out, u1_out);

  // ---- Z update: resblock1 ----
  dim3 cg(4, 32, 4);
  k_conv<<<cg, 256, 0, stream>>>(ZT,   w1a, Abuf, S + 0,   0, SS, SS, sthr);
  k_finstats<<<1, 64, 0, stream>>>(S + 0,   g1a, b1a, SS + 0);
  k_conv<<<cg, 256, 0, stream>>>(Abuf, w1b, Bb,   S + 64,  1, SS + 0,   SS + 32,  sthr);
  k_finstats<<<1, 64, 0, stream>>>(S + 64,  g1b, b1b, SS + 64);
  k_h1<<<32768, 256, 0, stream>>>(ZT, Bb, SS + 64, H1);
  // ---- resblock2 on soft-thresholded h1 -> z_next ----
  k_conv<<<cg, 256, 0, stream>>>(H1,   w2a, Abuf, S + 128, 2, SS, SS, sthr);
  k_finstats<<<1, 64, 0, stream>>>(S + 128, g2a, b2a, SS + 128);
  k_conv<<<cg, 256, 0, stream>>>(Abuf, w2b, Bb,   S + 192, 1, SS + 128, SS + 160, sthr);
  k_finstats<<<1, 64, 0, stream>>>(S + 192, g2b, b2b, SS + 192);
  // ---- resblock2 on h1 -> x_fb / symloss (runs before k_znext frees Abuf) ----
  k_conv<<<cg, 256, 0, stream>>>(H1,   w2a, Abuf, S + 256, 0, SS, SS, sthr);
  k_finstats<<<1, 64, 0, stream>>>(S + 256, g2a, b2a, SS + 256);
  k_conv<<<cg, 256, 0, stream>>>(Abuf, w2b, Bb6,  S + 320, 1, SS + 256, SS + 288, sthr);
  k_finstats<<<1, 64, 0, stream>>>(S + 320, g2b, b2b, SS + 320);
  k_sym<<<32768, 256, 0, stream>>>(H1, Bb6, SS + 320, ZT, sym_out);
  // ---- finals (write z_out over Abuf region, u2_out over Bb region) ----
  k_znext<<<32768, 256, 0, stream>>>(H1, Bb, SS + 192, sthr, u2, x_out, z_out, u2_out);
}

// Round 2
// 673.820 us; speedup vs baseline: 4.3050x; 4.3050x over previous
//
#include <hip/hip_runtime.h>
#include <math.h>

#define WDIM 256
#define HW   65536

struct cplx { float x, y; };
__device__ __forceinline__ cplx cmul(cplx a, cplx b){ return {a.x*b.x - a.y*b.y, a.x*b.y + a.y*b.x}; }
__device__ __forceinline__ cplx cadd(cplx a, cplx b){ return {a.x+b.x, a.y+b.y}; }
__device__ __forceinline__ cplx csub(cplx a, cplx b){ return {a.x-b.x, a.y-b.y}; }
__device__ __forceinline__ void swapc(cplx& a, cplx& b){ cplx t=a; a=b; b=t; }

typedef __attribute__((ext_vector_type(8))) short short8;
typedef __attribute__((ext_vector_type(4))) float float4v;

__device__ __forceinline__ unsigned short f2bf(float f){
  unsigned int u = __float_as_uint(f);
  unsigned int r = (u + 0x7FFFu + ((u >> 16) & 1u)) >> 16;
  return (unsigned short)r;
}
__device__ __forceinline__ float bf2f(unsigned short h){
  return __uint_as_float(((unsigned int)h) << 16);
}

// ---------------- 16-point FFT in registers (radix-2 DIT, bit-reversed input) ----
template<bool INV>
__device__ __forceinline__ void fft16(cplx v[16]) {
  const float C16[8] = {1.f, 0.9238795325112867f, 0.7071067811865476f, 0.3826834323650898f,
                        0.f, -0.3826834323650898f, -0.7071067811865476f, -0.9238795325112867f};
  const float S16[8] = {0.f, 0.3826834323650898f, 0.7071067811865476f, 0.9238795325112867f,
                        1.f, 0.9238795325112867f, 0.7071067811865476f, 0.3826834323650898f};
  swapc(v[1], v[8]); swapc(v[2], v[4]); swapc(v[3], v[12]);
  swapc(v[5], v[10]); swapc(v[7], v[14]); swapc(v[11], v[13]);
  #pragma unroll
  for (int s = 1; s <= 4; ++s) {
    const int m = 1 << s, half = m >> 1, step = 16 >> s;
    #pragma unroll
    for (int k = 0; k < 16; k += m) {
      #pragma unroll
      for (int j = 0; j < half; ++j) {
        cplx w = {C16[j*step], INV ? S16[j*step] : -S16[j*step]};
        cplx t = cmul(w, v[k+j+half]);
        v[k+j+half] = csub(v[k+j], t);
        v[k+j]      = cadd(v[k+j], t);
      }
    }
  }
}

template<bool INV>
__device__ void fft256_16(cplx v[16], int t, cplx* Yu) {
  fft16<INV>(v);
  float ang = (INV ? 6.283185307179586f : -6.283185307179586f) * (float)t * (1.0f/256.0f);
  float sn, cs; sincosf(ang, &sn, &cs);
  cplx wstep = {cs, sn}, w = {1.f, 0.f};
  #pragma unroll
  for (int c = 0; c < 16; ++c) { v[c] = cmul(v[c], w); w = cmul(w, wstep); }
  __syncthreads();
  #pragma unroll
  for (int c = 0; c < 16; ++c) Yu[t*17 + c] = v[c];
  __syncthreads();
  cplx z[16];
  #pragma unroll
  for (int b = 0; b < 16; ++b) z[b] = Yu[b*17 + t];
  fft16<INV>(z);
  #pragma unroll
  for (int d = 0; d < 16; ++d) v[d] = z[d];
  __syncthreads();
}

// ---------------- row FFT kernels -------------------------------------------
__global__ __launch_bounds__(256) void k_row_fwd_sub(const float* __restrict__ a,
                                                     const float* __restrict__ b,
                                                     cplx* __restrict__ out) {
  __shared__ cplx Y[16*280];
  int unit = threadIdx.x >> 4, t = threadIdx.x & 15;
  size_t base = (size_t)blockIdx.y*HW + (size_t)(blockIdx.x*16 + unit)*WDIM;
  cplx v[16];
  #pragma unroll
  for (int i = 0; i < 16; ++i) { size_t idx = base + i*16 + t; v[i] = {a[idx] - b[idx], 0.f}; }
  fft256_16<false>(v, t, Y + unit*280);
  #pragma unroll
  for (int d = 0; d < 16; ++d) out[base + t + 16*d] = v[d];
}

__global__ __launch_bounds__(256) void k_row_inv(const cplx* __restrict__ in,
                                                 cplx* __restrict__ out) {
  __shared__ cplx Y[16*280];
  int unit = threadIdx.x >> 4, t = threadIdx.x & 15;
  size_t base = (size_t)blockIdx.y*HW + (size_t)(blockIdx.x*16 + unit)*WDIM;
  cplx v[16];
  #pragma unroll
  for (int i = 0; i < 16; ++i) v[i] = in[base + i*16 + t];
  fft256_16<true>(v, t, Y + unit*280);
  #pragma unroll
  for (int d = 0; d < 16; ++d) out[base + t + 16*d] = {v[d].x*(1.f/256.f), v[d].y*(1.f/256.f)};
}

// ---------------- column FFT core -------------------------------------------
template<bool INV>
__device__ void col_core(const cplx* __restrict__ in, cplx* lds, cplx v[16], size_t planeBase) {
  int tid = threadIdx.x;
  #pragma unroll
  for (int i = 0; i < 16; ++i) {
    int idx = tid + 256*i; int h = idx >> 4, w = idx & 15;
    lds[h*17 + w] = in[planeBase + (size_t)h*WDIM + w];
  }
  __syncthreads();
  int u = tid >> 4, t = tid & 15;
  cplx vv[16];
  #pragma unroll
  for (int a = 0; a < 16; ++a) vv[a] = lds[(16*a + t)*17 + u];
  fft256_16<INV>(vv, t, lds + u*280);
  #pragma unroll
  for (int d = 0; d < 16; ++d) v[d] = vv[d];
}

__global__ __launch_bounds__(256) void k_col_fwd(cplx* __restrict__ buf) {
  __shared__ cplx lds[4480];
  size_t planeBase = (size_t)blockIdx.y*HW + blockIdx.x*16;
  cplx v[16];
  col_core<false>(buf, lds, v, planeBase);
  int u = threadIdx.x >> 4, t = threadIdx.x & 15;
  #pragma unroll
  for (int d = 0; d < 16; ++d) lds[(t + 16*d)*17 + u] = v[d];
  __syncthreads();
  int tid = threadIdx.x;
  #pragma unroll
  for (int i = 0; i < 16; ++i) {
    int idx = tid + 256*i; int h = idx >> 4, w = idx & 15;
    buf[planeBase + (size_t)h*WDIM + w] = lds[h*17 + w];
  }
}

__global__ __launch_bounds__(256) void k_col_inv_real_zt(const cplx* __restrict__ in,
                                                         const float* __restrict__ u2,
                                                         float* __restrict__ xout,
                                                         float* __restrict__ zt) {
  __shared__ cplx lds[4480];
  float* ldsf = (float*)lds;
  size_t planeBase = (size_t)blockIdx.y*HW + blockIdx.x*16;
  cplx v[16];
  col_core<true>(in, lds, v, planeBase);
  int u = threadIdx.x >> 4, t = threadIdx.x & 15;
  #pragma unroll
  for (int d = 0; d < 16; ++d) ldsf[(t + 16*d)*17 + u] = v[d].x * (1.f/256.f);
  __syncthreads();
  int tid = threadIdx.x;
  #pragma unroll
  for (int i = 0; i < 16; ++i) {
    int idx = tid + 256*i; int h = idx >> 4, w = idx & 15;
    size_t g = planeBase + (size_t)h*WDIM + w;
    float val = ldsf[h*17 + w];
    xout[g] = val;
    zt[g]   = val + u2[g];
  }
}

__global__ __launch_bounds__(256) void k_col_inv_abs(const cplx* __restrict__ in,
                                                     float* __restrict__ holo,
                                                     float* __restrict__ partials) {
  __shared__ cplx lds[4480];
  float* ldsf = (float*)lds;
  size_t planeBase = (size_t)blockIdx.y*HW + blockIdx.x*16;
  cplx v[16];
  col_core<true>(in, lds, v, planeBase);
  int u = threadIdx.x >> 4, t = threadIdx.x & 15;
  #pragma unroll
  for (int d = 0; d < 16; ++d) {
    float re = v[d].x*(1.f/256.f), im = v[d].y*(1.f/256.f);
    ldsf[(t + 16*d)*17 + u] = sqrtf(re*re + im*im);
  }
  __syncthreads();
  int tid = threadIdx.x;
  float mn = 1e30f, mx = -1e30f;
  #pragma unroll
  for (int i = 0; i < 16; ++i) {
    int idx = tid + 256*i; int h = idx >> 4, w = idx & 15;
    float val = ldsf[h*17 + w];
    holo[planeBase + (size_t)h*WDIM + w] = val;
    mn = fminf(mn, val); mx = fmaxf(mx, val);
  }
  __syncthreads();
  #pragma unroll
  for (int s = 1; s < 64; s <<= 1) { mn = fminf(mn, __shfl_xor(mn, s)); mx = fmaxf(mx, __shfl_xor(mx, s)); }
  if ((tid & 63) == 0) { ldsf[(tid>>6)*2] = mn; ldsf[(tid>>6)*2 + 1] = mx; }
  __syncthreads();
  if (tid == 0) {
    float a = fminf(fminf(ldsf[0], ldsf[2]), fminf(ldsf[4], ldsf[6]));
    float b = fmaxf(fmaxf(ldsf[1], ldsf[3]), fmaxf(ldsf[5], ldsf[7]));
    partials[(blockIdx.y*16 + blockIdx.x)*2]     = a;
    partials[(blockIdx.y*16 + blockIdx.x)*2 + 1] = b;
  }
}

__global__ __launch_bounds__(64) void k_mm_reduce(const float* __restrict__ partials,
                                                  float* __restrict__ minmax) {
  int t = threadIdx.x; int b = t >> 4, i = t & 15;
  float mn = partials[(b*16 + i)*2], mx = partials[(b*16 + i)*2 + 1];
  #pragma unroll
  for (int s = 1; s < 16; s <<= 1) { mn = fminf(mn, __shfl_xor(mn, s)); mx = fmaxf(mx, __shfl_xor(mx, s)); }
  if (i == 0) { minmax[b*2] = mn; minmax[b*2 + 1] = mx; }
}

// ---------------- Fourier-domain combine ------------------------------------
__global__ __launch_bounds__(256) void k_combine(cplx* __restrict__ W1,
                                                 const cplx* __restrict__ X1F,
                                                 const float* __restrict__ otr,
                                                 const float* __restrict__ oti,
                                                 const float* __restrict__ r1p,
                                                 const float* __restrict__ r2p) {
  int i = blockIdx.x*256 + threadIdx.x;
  int kw = i & 255, kh = (i >> 8) & 255, bd = i >> 16, b = bd >> 5;
  int kh2 = (256 - kh) & 255, kw2 = (256 - kw) & 255;
  int i2 = (bd << 16) | (kh2 << 8) | kw2;
  int p  = (b << 16) | (kh << 8) | kw;
  int p2 = (b << 16) | (kh2 << 8) | kw2;
  cplx A = X1F[p], Am = X1F[p2];
  float or1 = otr[i], oi1 = oti[i], or2 = otr[i2], oi2 = oti[i2];
  float hr = 0.5f*(A.x*or1 + A.y*oi1 + Am.x*or2 + Am.y*oi2);
  float hi = 0.5f*(A.y*or1 - A.x*oi1 + Am.x*oi2 - Am.y*or2);
  cplx z2 = W1[i];
  float rho1 = r1p[0], rho2 = r2p[0];
  float den = 1.0f / (rho2 + rho1*(or1*or1 + oi1*oi1));
  W1[i] = {(rho1*hr + rho2*z2.x)*den, (rho1*hi + rho2*z2.y)*den};
}

__global__ __launch_bounds__(256) void k_hf(const cplx* __restrict__ XF,
                                            const float* __restrict__ otr,
                                            const float* __restrict__ oti,
                                            cplx* __restrict__ HF) {
  int j = blockIdx.x*256 + threadIdx.x;
  int b = j >> 16, kh = (j >> 8) & 255, kw = j & 255;
  int kh2 = (256 - kh) & 255, kw2 = (256 - kw) & 255;
  float ar = 0.f, ai = 0.f;
  for (int d = 0; d < 32; ++d) {
    int base = ((b*32 + d) << 16);
    int idx  = base | (kh << 8) | kw;
    int idx2 = base | (kh2 << 8) | kw2;
    cplx Xk = XF[idx], Xm = XF[idx2];
    float xr = 0.5f*(Xk.x + Xm.x), xi = 0.5f*(Xk.y - Xm.y);
    float o_r = otr[idx], o_i = oti[idx];
    ar += xr*o_r - xi*o_i;
    ai += xr*o_i + xi*o_r;
  }
  HF[j] = {ar, ai};
}

// ---------------- Phi update -------------------------------------------------
__global__ __launch_bounds__(256) void k_bisect(const float* __restrict__ holo,
                                                const float* __restrict__ minmax,
                                                const float* __restrict__ u1,
                                                const int* __restrict__ K1,
                                                const float* __restrict__ r1p,
                                                float* __restrict__ phi_out,
                                                float* __restrict__ u1_out) {
  int i = blockIdx.x*256 + threadIdx.x;
  int b = i >> 16;
  float mn = minmax[2*b], mx = minmax[2*b + 1];
  float fp = (holo[i] - mn) / (mx - mn);
  float pt = fp + u1[i];
  float K1f = (float)K1[i];
  float K0 = 1.f - K1f;
  float rho1 = r1p[0];
  bool ind0i = (K1f == 0.f);
  bool ind0 = ind0i;
  float pmin = 1e-5f, pmax = 100.f, pave = 0.5f*(pmin + pmax);
  #pragma unroll 1
  for (int it = 0; it < 30; ++it) {
    float e = expf(pave);
    float t = (K0 - K1f/(e - 1.f)) + rho1*(pave - pt);
    bool ind1 = !ind0;
    if (t > 0.f && ind1) pmin = pave;
    if (t < 0.f && ind1) pmax = pave;
    ind0 = ind0 || (t == 0.f && ind1);
    if (!ind0) pave = 0.5f*(pmin + pmax);
  }
  float pn = ind0i ? (pt - K0/rho1) : pave;
  phi_out[i] = pn;
  u1_out[i]  = u1[i] + pn - fp;
}

// =============================================================================
//                        Z-update: MFMA conv pipeline
// Channel-last bf16 activations: elem addr = ((b*65536 + h*256 + w)*32 + ic)
// =============================================================================

// weight prep: [oc][ic][3][3] fp32 -> Aprep[wsel][tap][oc][ic] bf16
__global__ __launch_bounds__(256) void k_wprep(const float* __restrict__ w1a,
                                               const float* __restrict__ w1b,
                                               const float* __restrict__ w2a,
                                               const float* __restrict__ w2b,
                                               unsigned short* __restrict__ Ap) {
  int idx = blockIdx.x*256 + threadIdx.x;
  if (idx >= 4*9216) return;
  int wsel = idx / 9216, r = idx - wsel*9216;
  const float* w = wsel==0 ? w1a : wsel==1 ? w1b : wsel==2 ? w2a : w2b;
  int tap = r / 1024, r2 = r - tap*1024, oc = r2 >> 5, ic = r2 & 31;
  Ap[idx] = f2bf(w[(oc*32 + ic)*9 + tap]);
}

// planar fp32 -> channel-last bf16 (tile transpose). grid (1024, 4), 256 thr.
__global__ __launch_bounds__(256) void k_cl0(const float* __restrict__ in,
                                             unsigned short* __restrict__ outCL) {
  __shared__ float t1[32*66];
  int tid = threadIdx.x;
  size_t b = blockIdx.y;
  int px0 = blockIdx.x * 64;
  #pragma unroll
  for (int i = 0; i < 2; ++i) {
    int ch = tid + i*256; int c = ch >> 4, p4 = (ch & 15)*4;
    float4 v = *(const float4*)(in + ((b*32 + c)<<16) + px0 + p4);
    t1[c*66 + p4] = v.x; t1[c*66+p4+1] = v.y; t1[c*66+p4+2] = v.z; t1[c*66+p4+3] = v.w;
  }
  __syncthreads();
  int px = tid >> 2, cg = tid & 3;
  unsigned short o[8];
  #pragma unroll
  for (int j = 0; j < 8; ++j) o[j] = f2bf(t1[(cg*8+j)*66 + px]);
  *(uint4*)(outCL + ((((b<<16) + px0 + px))<<5) + cg*8) = *(uint4*)o;
}

// MFMA conv 3x3 32->32, SAME. grid (4, 64, 4) = 1024 blocks, 256 thr (4 waves).
// Input staged with fused transform: mode 0 none, 1 BN+lrelu, 2 soft-threshold.
// Raw bf16 CL output + per-block BN stat partials (no atomics).
#define CONV_R 4
__global__ __launch_bounds__(256, 4) void k_conv(const unsigned short* __restrict__ inCL,
                                                 const unsigned short* __restrict__ Aprep,
                                                 unsigned short* __restrict__ outCL,
                                                 float* __restrict__ part,
                                                 int mode,
                                                 const float* __restrict__ scsh,
                                                 const float* __restrict__ thrp) {
  __shared__ unsigned short tile[6*66*32];   // 25344 B, [row][col][ic]
  __shared__ float sred[4][16][2];
  int tid = threadIdx.x;
  int bx = blockIdx.x, by = blockIdx.y, bz = blockIdx.z;
  int w0 = bx*64, h0 = by*CONV_R;
  float thr = (mode == 2) ? thrp[0] : 0.f;

  for (int idx = tid; idx < 6*264; idx += 256) {
    int lrow = idx/264, rem = idx - lrow*264;
    int lcol = rem >> 2, m = rem & 3;
    int grow = h0 - 1 + lrow, gcol = w0 - 1 + lcol;
    uint4 val = {0,0,0,0};
    if (grow >= 0 && grow < 256 && gcol >= 0 && gcol < 256) {
      uint4 raw = *(const uint4*)(inCL + (((size_t)(bz<<16) + (grow<<8) + gcol)<<5) + m*8);
      if (mode == 0) val = raw;
      else {
        unsigned short h8[8]; *(uint4*)h8 = raw;
        #pragma unroll
        for (int j = 0; j < 8; ++j) {
          float v = bf2f(h8[j]);
          if (mode == 1) { int ic = m*8+j; v = v*scsh[ic] + scsh[32+ic]; v = v > 0.f ? v : 0.01f*v; }
          else { float s = fabsf(v) - thr; s = s > 0.f ? s : 0.f; v = copysignf(s, v); }
          h8[j] = f2bf(v);
        }
        val = *(uint4*)h8;
      }
    }
    *(uint4*)&tile[(size_t)idx*8] = val;   // (lrow*66+lcol)*32 + m*8 == idx*8
  }

  int lane = tid & 63, w = tid >> 6;
  int q = lane >> 4, ln = lane & 15;
  int ocH = w & 1, s0 = w >> 1;
  short8 afrag[9];
  #pragma unroll
  for (int t = 0; t < 9; ++t)
    afrag[t] = *(const short8*)(Aprep + ((t*32 + ocH*16 + ln)*32 + q*8));
  __syncthreads();

  float sacc[4] = {0,0,0,0}, s2acc[4] = {0,0,0,0};
  #pragma unroll
  for (int r = 0; r < CONV_R; ++r) {
    #pragma unroll
    for (int si = 0; si < 2; ++si) {
      int s = s0 + si*2;
      float4v acc = {0.f, 0.f, 0.f, 0.f};
      #pragma unroll
      for (int t = 0; t < 9; ++t) {
        int dy = t/3, dx = t - dy*3;
        int lrow = r + dy, lcol = s*16 + ln + dx;
        const short8 bfrag = *(const short8*)&tile[(lrow*66 + lcol)*32 + q*8];
        acc = __builtin_amdgcn_mfma_f32_16x16x32_bf16(afrag[t], bfrag, acc, 0, 0, 0);
      }
      int px = w0 + s*16 + ln, row = h0 + r;
      size_t obase = ((((size_t)(bz<<16) + (row<<8) + px))<<5) + ocH*16 + q*4;
      unsigned short o4[4];
      #pragma unroll
      for (int u = 0; u < 4; ++u) { o4[u] = f2bf(acc[u]); sacc[u] += acc[u]; s2acc[u] += acc[u]*acc[u]; }
      *(uint2*)(outCL + obase) = *(uint2*)o4;
    }
  }

  #pragma unroll
  for (int u = 0; u < 4; ++u) {
    float a = sacc[u], b2 = s2acc[u];
    #pragma unroll
    for (int mq = 1; mq < 16; mq <<= 1) { a += __shfl_xor(a, mq); b2 += __shfl_xor(b2, mq); }
    if (ln == 0) { sred[w][q*4+u][0] = a; sred[w][q*4+u][1] = b2; }
  }
  __syncthreads();
  if (tid < 64) {
    int ocH2 = tid >> 5, i16 = (tid >> 1) & 15, st = tid & 1;
    float tot = sred[ocH2][i16][st] + sred[ocH2+2][i16][st];
    int oc = ocH2*16 + i16;
    int blk = ((bz<<6) + by)*4 + bx;
    part[(oc*2+st)*1024 + blk] = tot;
  }
}

// reduce partials -> BN scale/shift
__global__ __launch_bounds__(256) void k_finstats2(const float* __restrict__ part,
                                                   const float* __restrict__ g,
                                                   const float* __restrict__ beta,
                                                   float* __restrict__ SS) {
  __shared__ float red[64];
  int t = threadIdx.x, p = t >> 2, ch = t & 3;
  const float4* pp = (const float4*)(part + p*1024 + ch*256);
  float s = 0.f;
  for (int i = 0; i < 64; ++i) { float4 v = pp[i]; s += v.x + v.y + v.z + v.w; }
  s += __shfl_xor(s, 1); s += __shfl_xor(s, 2);
  if (ch == 0) red[p] = s;
  __syncthreads();
  if (t < 32) {
    const float N = 262144.f;
    float mean = red[t*2] / N;
    float var  = red[t*2+1] / N - mean*mean;
    float sc = g[t] * rsqrtf(var + 1e-5f);
    SS[t] = sc; SS[32+t] = beta[t] - mean*sc;
  }
}

// h1 = lrelu(zt + BN1b(c2)), pure channel-last elementwise
__global__ __launch_bounds__(256) void k_h1cl(const unsigned short* __restrict__ zt,
                                              const unsigned short* __restrict__ c2,
                                              const float* __restrict__ SS,
                                              unsigned short* __restrict__ h1) {
  int idx = blockIdx.x*256 + threadIdx.x;
  int cg = idx & 3;
  uint4 za = *(const uint4*)(zt + (size_t)idx*8);
  uint4 ca = *(const uint4*)(c2 + (size_t)idx*8);
  unsigned short zs[8], cs[8], os[8];
  *(uint4*)zs = za; *(uint4*)cs = ca;
  #pragma unroll
  for (int j = 0; j < 8; ++j) {
    int c = cg*8 + j;
    float v = bf2f(zs[j]) + bf2f(cs[j])*SS[c] + SS[32+c];
    v = v > 0.f ? v : 0.01f*v;
    os[j] = f2bf(v);
  }
  *(uint4*)(h1 + (size_t)idx*8) = *(uint4*)os;
}

// z = lrelu(soft(h1)+BN(c4)); u2n = u2 + z - x  (planar fp32 outputs)
__global__ __launch_bounds__(256) void k_finalA(const unsigned short* __restrict__ h1,
                                                const unsigned short* __restrict__ c4,
                                                const float* __restrict__ SS,
                                                const float* __restrict__ thrp,
                                                const float* __restrict__ u2,
                                                const float* __restrict__ x,
                                                float* __restrict__ zout,
                                                float* __restrict__ u2out) {
  __shared__ float zT[32*66];
  int tid = threadIdx.x;
  size_t b = blockIdx.y;
  int px0 = blockIdx.x*64;
  float thr = thrp[0];
  int px = tid >> 2, cg = tid & 3;
  size_t cbase = ((((b<<16) + px0 + px))<<5) + cg*8;
  uint4 ha = *(const uint4*)(h1 + cbase);
  uint4 ca = *(const uint4*)(c4 + cbase);
  unsigned short hs[8], cs[8];
  *(uint4*)hs = ha; *(uint4*)cs = ca;
  #pragma unroll
  for (int j = 0; j < 8; ++j) {
    int c = cg*8+j;
    float hv = bf2f(hs[j]);
    float s = fabsf(hv) - thr; s = s > 0.f ? s : 0.f;
    float th = copysignf(s, hv);
    float v = th + bf2f(cs[j])*SS[c] + SS[32+c];
    zT[c*66 + px] = v > 0.f ? v : 0.01f*v;
  }
  __syncthreads();
  #pragma unroll
  for (int i = 0; i < 2; ++i) {
    int ch = tid + i*256; int c = ch >> 4, p4 = (ch & 15)*4;
    size_t g = ((b*32 + c)<<16) + px0 + p4;
    float4 uv = *(const float4*)(u2 + g);
    float4 xv = *(const float4*)(x + g);
    float4 zv = { zT[c*66+p4], zT[c*66+p4+1], zT[c*66+p4+2], zT[c*66+p4+3] };
    float4 un = { uv.x+zv.x-xv.x, uv.y+zv.y-xv.y, uv.z+zv.z-xv.z, uv.w+zv.w-xv.w };
    *(float4*)(zout + g) = zv;
    *(float4*)(u2out + g) = un;
  }
}

// xfb = lrelu(h1 + BN(c6)); sym = xfb - zt  (planar fp32 output)
__global__ __launch_bounds__(256) void k_finalB(const unsigned short* __restrict__ h1,
                                                const unsigned short* __restrict__ c6,
                                                const float* __restrict__ SS,
                                                const unsigned short* __restrict__ ztcl,
                                                float* __restrict__ symout) {
  __shared__ float sT[32*66];
  int tid = threadIdx.x;
  size_t b = blockIdx.y;
  int px0 = blockIdx.x*64;
  int px = tid >> 2, cg = tid & 3;
  size_t cbase = ((((b<<16) + px0 + px))<<5) + cg*8;
  uint4 ha = *(const uint4*)(h1 + cbase);
  uint4 ca = *(const uint4*)(c6 + cbase);
  uint4 za = *(const uint4*)(ztcl + cbase);
  unsigned short hs[8], cs[8], zs[8];
  *(uint4*)hs = ha; *(uint4*)cs = ca; *(uint4*)zs = za;
  #pragma unroll
  for (int j = 0; j < 8; ++j) {
    int c = cg*8+j;
    float v = bf2f(hs[j]) + bf2f(cs[j])*SS[c] + SS[32+c];
    v = v > 0.f ? v : 0.01f*v;
    sT[c*66 + px] = v - bf2f(zs[j]);
  }
  __syncthreads();
  #pragma unroll
  for (int i = 0; i < 2; ++i) {
    int ch = tid + i*256; int c = ch >> 4, p4 = (ch & 15)*4;
    size_t g = ((b*32 + c)<<16) + px0 + p4;
    float4 sv = { sT[c*66+p4], sT[c*66+p4+1], sT[c*66+p4+2], sT[c*66+p4+3] };
    *(float4*)(symout + g) = sv;
  }
}

// ================================================================================
extern "C" void kernel_launch(void* const* d_in, const int* in_sizes, int n_in,
                              void* d_out, int out_size, void* d_ws, size_t ws_size,
                              hipStream_t stream) {
  const float* phi  = (const float*)d_in[1];
  const float* z    = (const float*)d_in[2];
  const float* u1   = (const float*)d_in[3];
  const float* u2   = (const float*)d_in[4];
  const float* otr  = (const float*)d_in[5];
  const float* oti  = (const float*)d_in[6];
  const int*   K1   = (const int*)d_in[7];
  const float* rho1 = (const float*)d_in[8];
  const float* rho2 = (const float*)d_in[9];
  const float* sthr = (const float*)d_in[10];
  const float* w1a = (const float*)d_in[11];
  const float* g1a = (const float*)d_in[12];
  const float* b1a = (const float*)d_in[13];
  const float* w1b = (const float*)d_in[14];
  const float* g1b = (const float*)d_in[15];
  const float* b1b = (const float*)d_in[16];
  const float* w2a = (const float*)d_in[17];
  const float* g2a = (const float*)d_in[18];
  const float* b2a = (const float*)d_in[19];
  const float* w2b = (const float*)d_in[20];
  const float* g2b = (const float*)d_in[21];
  const float* b2b = (const float*)d_in[22];

  float* out = (float*)d_out;
  float* x_out   = out;                 // [B,D,H,W]
  float* phi_out = out + 8388608;
  float* z_out   = out + 8650752;
  float* u1_out  = out + 17039360;
  float* u2_out  = out + 17301504;
  float* sym_out = out + 25690112;

  char* ws = (char*)d_ws;
  cplx*  W1    = (cplx*)ws;                          // 64 MiB
  cplx*  X1R   = (cplx*)(ws + 67108864);             // 2 MB
  cplx*  HFT   = (cplx*)(ws + 69206016);             // 2 MB
  float* holo  = (float*)(ws + 71303168);            // 1 MB (reused post-bisect)
  float* partmm= (float*)(ws + 72351744);
  float* mm    = (float*)(ws + 72355840);
  float* ZT    = (float*)ws;                         // planar zt, reuses W1 lo

  // conv-phase buffers (all dead-region reuse):
  unsigned short* Ap    = (unsigned short*)(ws + 71303168);           // 73728 B (ex-holo)
  float*          part  = (float*)(ws + 71434240);                    // 256 KB
  float*          SSb   = (float*)(ws + 71696384);                    // 6*64 floats
  unsigned short* ZTcl  = (unsigned short*)(ws + 33554432);           // 16 MiB (ex-W1 hi)
  unsigned short* H1cl  = (unsigned short*)(ws + 50331648);           // 16 MiB (ex-W1 hi)
  unsigned short* C4cl  = (unsigned short*)(ws + 0);                  // ex-ZT planar
  unsigned short* C2cl  = (unsigned short*)(ws + 16777216);           // ex-ZT planar
  unsigned short* C135  = (unsigned short*)z_out;                     // scratch, dead pre-finalA
  unsigned short* C6cl  = (unsigned short*)u2_out;                    // dead pre-finalA (B first)
  cplx* W2lo = (cplx*)z_out;
  cplx* W2hi = (cplx*)sym_out;

  // ---- X update (Fourier domain) ----
  k_row_fwd_sub<<<dim3(16, 4),   256, 0, stream>>>(phi, u1, X1R);
  k_col_fwd    <<<dim3(16, 4),   256, 0, stream>>>(X1R);
  k_row_fwd_sub<<<dim3(16, 128), 256, 0, stream>>>(z, u2, W1);
  k_col_fwd    <<<dim3(16, 128), 256, 0, stream>>>(W1);
  k_combine    <<<32768, 256, 0, stream>>>(W1, X1R, otr, oti, rho1, rho2);
  k_hf         <<<1024, 256, 0, stream>>>(W1, otr, oti, X1R);
  k_row_inv    <<<dim3(16, 4),   256, 0, stream>>>(X1R, HFT);
  k_col_inv_abs<<<dim3(16, 4),   256, 0, stream>>>(HFT, holo, partmm);
  k_mm_reduce  <<<1, 64, 0, stream>>>(partmm, mm);
  k_row_inv    <<<dim3(16, 64), 256, 0, stream>>>(W1, W2lo);
  k_row_inv    <<<dim3(16, 64), 256, 0, stream>>>(W1 + (size_t)64*HW, W2hi);
  k_col_inv_real_zt<<<dim3(16, 64), 256, 0, stream>>>(W2lo, u2, x_out, ZT);
  k_col_inv_real_zt<<<dim3(16, 64), 256, 0, stream>>>(W2hi, u2 + (size_t)64*HW,
                                                      x_out + (size_t)64*HW, ZT + (size_t)64*HW);
  // ---- Phi update ----
  k_bisect<<<1024, 256, 0, stream>>>(holo, mm, u1, K1, rho1, phi_out, u1_out);

  // ---- Z update ----
  k_wprep<<<144, 256, 0, stream>>>(w1a, w1b, w2a, w2b, Ap);
  k_cl0<<<dim3(1024, 4), 256, 0, stream>>>(ZT, ZTcl);

  dim3 cg(4, 64, 4);
  k_conv<<<cg, 256, 0, stream>>>(ZTcl, Ap + 0,      C135, part, 0, SSb,       sthr);
  k_finstats2<<<1, 256, 0, stream>>>(part, g1a, b1a, SSb + 0);
  k_conv<<<cg, 256, 0, stream>>>(C135, Ap + 9216,   C2cl, part, 1, SSb + 0,   sthr);
  k_finstats2<<<1, 256, 0, stream>>>(part, g1b, b1b, SSb + 64);
  k_h1cl<<<4096, 256, 0, stream>>>(ZTcl, C2cl, SSb + 64, H1cl);

  k_conv<<<cg, 256, 0, stream>>>(H1cl, Ap + 18432,  C135, part, 2, SSb,       sthr);
  k_finstats2<<<1, 256, 0, stream>>>(part, g2a, b2a, SSb + 128);
  k_conv<<<cg, 256, 0, stream>>>(C135, Ap + 27648,  C4cl, part, 1, SSb + 128, sthr);
  k_finstats2<<<1, 256, 0, stream>>>(part, g2b, b2b, SSb + 192);

  k_conv<<<cg, 256, 0, stream>>>(H1cl, Ap + 18432,  C135, part, 0, SSb,       sthr);
  k_finstats2<<<1, 256, 0, stream>>>(part, g2a, b2a, SSb + 256);
  k_conv<<<cg, 256, 0, stream>>>(C135, Ap + 27648,  C6cl, part, 1, SSb + 256, sthr);
  k_finstats2<<<1, 256, 0, stream>>>(part, g2b, b2b, SSb + 320);

  k_finalB<<<dim3(1024, 4), 256, 0, stream>>>(H1cl, C6cl, SSb + 320, ZTcl, sym_out);
  k_finalA<<<dim3(1024, 4), 256, 0, stream>>>(H1cl, C4cl, SSb + 192, sthr, u2, x_out,
                                              z_out, u2_out);
}

// Round 3
// 599.921 us; speedup vs baseline: 4.8353x; 1.1232x over previous
//
#include <hip/hip_runtime.h>
#include <math.h>

#define WDIM 256
#define HW   65536

struct cplx { float x, y; };
__device__ __forceinline__ cplx cmul(cplx a, cplx b){ return {a.x*b.x - a.y*b.y, a.x*b.y + a.y*b.x}; }
__device__ __forceinline__ cplx cadd(cplx a, cplx b){ return {a.x+b.x, a.y+b.y}; }
__device__ __forceinline__ cplx csub(cplx a, cplx b){ return {a.x-b.x, a.y-b.y}; }
__device__ __forceinline__ void swapc(cplx& a, cplx& b){ cplx t=a; a=b; b=t; }

typedef __attribute__((ext_vector_type(8))) short short8;
typedef __attribute__((ext_vector_type(4))) float float4v;

__device__ __forceinline__ unsigned short f2bf(float f){
  unsigned int u = __float_as_uint(f);
  unsigned int r = (u + 0x7FFFu + ((u >> 16) & 1u)) >> 16;
  return (unsigned short)r;
}
__device__ __forceinline__ float bf2f(unsigned short h){
  return __uint_as_float(((unsigned int)h) << 16);
}

// ---------------- 16-point FFT in registers (radix-2 DIT, bit-reversed input) ----
template<bool INV>
__device__ __forceinline__ void fft16(cplx v[16]) {
  const float C16[8] = {1.f, 0.9238795325112867f, 0.7071067811865476f, 0.3826834323650898f,
                        0.f, -0.3826834323650898f, -0.7071067811865476f, -0.9238795325112867f};
  const float S16[8] = {0.f, 0.3826834323650898f, 0.7071067811865476f, 0.9238795325112867f,
                        1.f, 0.9238795325112867f, 0.7071067811865476f, 0.3826834323650898f};
  swapc(v[1], v[8]); swapc(v[2], v[4]); swapc(v[3], v[12]);
  swapc(v[5], v[10]); swapc(v[7], v[14]); swapc(v[11], v[13]);
  #pragma unroll
  for (int s = 1; s <= 4; ++s) {
    const int m = 1 << s, half = m >> 1, step = 16 >> s;
    #pragma unroll
    for (int k = 0; k < 16; k += m) {
      #pragma unroll
      for (int j = 0; j < half; ++j) {
        cplx w = {C16[j*step], INV ? S16[j*step] : -S16[j*step]};
        cplx t = cmul(w, v[k+j+half]);
        v[k+j+half] = csub(v[k+j], t);
        v[k+j]      = cadd(v[k+j], t);
      }
    }
  }
}

template<bool INV>
__device__ void fft256_16(cplx v[16], int t, cplx* Yu) {
  fft16<INV>(v);
  float ang = (INV ? 6.283185307179586f : -6.283185307179586f) * (float)t * (1.0f/256.0f);
  float sn, cs; sincosf(ang, &sn, &cs);
  cplx wstep = {cs, sn}, w = {1.f, 0.f};
  #pragma unroll
  for (int c = 0; c < 16; ++c) { v[c] = cmul(v[c], w); w = cmul(w, wstep); }
  __syncthreads();
  #pragma unroll
  for (int c = 0; c < 16; ++c) Yu[t*17 + c] = v[c];
  __syncthreads();
  cplx z[16];
  #pragma unroll
  for (int b = 0; b < 16; ++b) z[b] = Yu[b*17 + t];
  fft16<INV>(z);
  #pragma unroll
  for (int d = 0; d < 16; ++d) v[d] = z[d];
  __syncthreads();
}

// ---------------- row FFT kernels -------------------------------------------
// small path: real a-b -> row FFT (one plane per blockIdx.y)
__global__ __launch_bounds__(256) void k_row_fwd_sub(const float* __restrict__ a,
                                                     const float* __restrict__ b,
                                                     cplx* __restrict__ out) {
  __shared__ cplx Y[16*280];
  int unit = threadIdx.x >> 4, t = threadIdx.x & 15;
  size_t base = (size_t)blockIdx.y*HW + (size_t)(blockIdx.x*16 + unit)*WDIM;
  cplx v[16];
  #pragma unroll
  for (int i = 0; i < 16; ++i) { size_t idx = base + i*16 + t; v[i] = {a[idx] - b[idx], 0.f}; }
  fft256_16<false>(v, t, Y + unit*280);
  #pragma unroll
  for (int d = 0; d < 16; ++d) out[base + t + 16*d] = v[d];
}

// packed path: planes (2p, 2p+1) of (a-b) as re+i*im; blockIdx.y = b*16+p
__global__ __launch_bounds__(256) void k_row_fwd_sub_p(const float* __restrict__ a,
                                                       const float* __restrict__ b,
                                                       cplx* __restrict__ out) {
  __shared__ cplx Y[16*280];
  int unit = threadIdx.x >> 4, t = threadIdx.x & 15;
  int bp = blockIdx.y; int bb = bp >> 4, p = bp & 15;
  size_t rowoff = (size_t)(blockIdx.x*16 + unit)*WDIM;
  size_t base0 = ((size_t)(bb*32 + 2*p))*HW + rowoff;
  size_t base1 = base0 + HW;
  size_t baseo = (size_t)bp*HW + rowoff;
  cplx v[16];
  #pragma unroll
  for (int i = 0; i < 16; ++i) {
    size_t o = i*16 + t;
    v[i] = {a[base0+o] - b[base0+o], a[base1+o] - b[base1+o]};
  }
  fft256_16<false>(v, t, Y + unit*280);
  #pragma unroll
  for (int d = 0; d < 16; ++d) out[baseo + t + 16*d] = v[d];
}

__global__ __launch_bounds__(256) void k_row_inv(const cplx* __restrict__ in,
                                                 cplx* __restrict__ out) {
  __shared__ cplx Y[16*280];
  int unit = threadIdx.x >> 4, t = threadIdx.x & 15;
  size_t base = (size_t)blockIdx.y*HW + (size_t)(blockIdx.x*16 + unit)*WDIM;
  cplx v[16];
  #pragma unroll
  for (int i = 0; i < 16; ++i) v[i] = in[base + i*16 + t];
  fft256_16<true>(v, t, Y + unit*280);
  #pragma unroll
  for (int d = 0; d < 16; ++d) out[base + t + 16*d] = {v[d].x*(1.f/256.f), v[d].y*(1.f/256.f)};
}

// ---------------- column FFT core -------------------------------------------
template<bool INV>
__device__ void col_core(const cplx* __restrict__ in, cplx* lds, cplx v[16], size_t planeBase) {
  int tid = threadIdx.x;
  #pragma unroll
  for (int i = 0; i < 16; ++i) {
    int idx = tid + 256*i; int h = idx >> 4, w = idx & 15;
    lds[h*17 + w] = in[planeBase + (size_t)h*WDIM + w];
  }
  __syncthreads();
  int u = tid >> 4, t = tid & 15;
  cplx vv[16];
  #pragma unroll
  for (int a = 0; a < 16; ++a) vv[a] = lds[(16*a + t)*17 + u];
  fft256_16<INV>(vv, t, lds + u*280);
  #pragma unroll
  for (int d = 0; d < 16; ++d) v[d] = vv[d];
}

__global__ __launch_bounds__(256) void k_col_fwd(cplx* __restrict__ buf) {
  __shared__ cplx lds[4480];
  size_t planeBase = (size_t)blockIdx.y*HW + blockIdx.x*16;
  cplx v[16];
  col_core<false>(buf, lds, v, planeBase);
  int u = threadIdx.x >> 4, t = threadIdx.x & 15;
  #pragma unroll
  for (int d = 0; d < 16; ++d) lds[(t + 16*d)*17 + u] = v[d];
  __syncthreads();
  int tid = threadIdx.x;
  #pragma unroll
  for (int i = 0; i < 16; ++i) {
    int idx = tid + 256*i; int h = idx >> 4, w = idx & 15;
    buf[planeBase + (size_t)h*WDIM + w] = lds[h*17 + w];
  }
}

// packed inverse cols: plane bp=(b,p) -> x[b,2p]=Re, x[b,2p+1]=Im; zt = x+u2
__global__ __launch_bounds__(256) void k_col_inv_xzt_p(const cplx* __restrict__ in,
                                                       const float* __restrict__ u2,
                                                       float* __restrict__ xout,
                                                       float* __restrict__ zt) {
  __shared__ cplx lds[4480];
  int bp = blockIdx.y; int bb = bp >> 4, p = bp & 15;
  size_t planeBase = (size_t)bp*HW + blockIdx.x*16;
  cplx v[16];
  col_core<true>(in, lds, v, planeBase);
  int u = threadIdx.x >> 4, t = threadIdx.x & 15;
  #pragma unroll
  for (int d = 0; d < 16; ++d) lds[(t + 16*d)*17 + u] = {v[d].x*(1.f/256.f), v[d].y*(1.f/256.f)};
  __syncthreads();
  int tid = threadIdx.x;
  size_t out0 = ((size_t)(bb*32 + 2*p))*HW + blockIdx.x*16;
  size_t out1 = out0 + HW;
  #pragma unroll
  for (int i = 0; i < 16; ++i) {
    int idx = tid + 256*i; int h = idx >> 4, w = idx & 15;
    cplx val = lds[h*17 + w];
    size_t g0 = out0 + (size_t)h*WDIM + w;
    size_t g1 = out1 + (size_t)h*WDIM + w;
    xout[g0] = val.x; zt[g0] = val.x + u2[g0];
    xout[g1] = val.y; zt[g1] = val.y + u2[g1];
  }
}

// inverse cols -> |.| (holo) + per-block min/max partials (small path)
__global__ __launch_bounds__(256) void k_col_inv_abs(const cplx* __restrict__ in,
                                                     float* __restrict__ holo,
                                                     float* __restrict__ partials) {
  __shared__ cplx lds[4480];
  float* ldsf = (float*)lds;
  size_t planeBase = (size_t)blockIdx.y*HW + blockIdx.x*16;
  cplx v[16];
  col_core<true>(in, lds, v, planeBase);
  int u = threadIdx.x >> 4, t = threadIdx.x & 15;
  #pragma unroll
  for (int d = 0; d < 16; ++d) {
    float re = v[d].x*(1.f/256.f), im = v[d].y*(1.f/256.f);
    ldsf[(t + 16*d)*17 + u] = sqrtf(re*re + im*im);
  }
  __syncthreads();
  int tid = threadIdx.x;
  float mn = 1e30f, mx = -1e30f;
  #pragma unroll
  for (int i = 0; i < 16; ++i) {
    int idx = tid + 256*i; int h = idx >> 4, w = idx & 15;
    float val = ldsf[h*17 + w];
    holo[planeBase + (size_t)h*WDIM + w] = val;
    mn = fminf(mn, val); mx = fmaxf(mx, val);
  }
  __syncthreads();
  #pragma unroll
  for (int s = 1; s < 64; s <<= 1) { mn = fminf(mn, __shfl_xor(mn, s)); mx = fmaxf(mx, __shfl_xor(mx, s)); }
  if ((tid & 63) == 0) { ldsf[(tid>>6)*2] = mn; ldsf[(tid>>6)*2 + 1] = mx; }
  __syncthreads();
  if (tid == 0) {
    float a = fminf(fminf(ldsf[0], ldsf[2]), fminf(ldsf[4], ldsf[6]));
    float b = fmaxf(fmaxf(ldsf[1], ldsf[3]), fmaxf(ldsf[5], ldsf[7]));
    partials[(blockIdx.y*16 + blockIdx.x)*2]     = a;
    partials[(blockIdx.y*16 + blockIdx.x)*2 + 1] = b;
  }
}

__global__ __launch_bounds__(64) void k_mm_reduce(const float* __restrict__ partials,
                                                  float* __restrict__ minmax) {
  int t = threadIdx.x; int b = t >> 4, i = t & 15;
  float mn = partials[(b*16 + i)*2], mx = partials[(b*16 + i)*2 + 1];
  #pragma unroll
  for (int s = 1; s < 16; s <<= 1) { mn = fminf(mn, __shfl_xor(mn, s)); mx = fmaxf(mx, __shfl_xor(mx, s)); }
  if (i == 0) { minmax[b*2] = mn; minmax[b*2 + 1] = mx; }
}

// ---------------- fused combine + HF ----------------------------------------
// P: packed forward spectrum [b*16+p][k].  Q: packed Hermitian-part X spectrum.
// Xh_d[k] = (rho1*G_d[k] + rho2*Z_d[k]) * 0.5*(1/den_d[k] + 1/den_d[-k])
// HF[b,k] = sum_d Xh_d[k]*otf_d[k]
__global__ __launch_bounds__(256) void k_combine_hf(const cplx* __restrict__ P,
                                                    cplx* __restrict__ Q,
                                                    const cplx* __restrict__ X1F,
                                                    const float* __restrict__ otr,
                                                    const float* __restrict__ oti,
                                                    const float* __restrict__ r1p,
                                                    const float* __restrict__ r2p,
                                                    cplx* __restrict__ HF) {
  int j = blockIdx.x*256 + threadIdx.x;     // [B*HW)
  int b = j >> 16, k = j & 65535;
  int kh = k >> 8, kw = k & 255;
  int k2 = (((256 - kh) & 255) << 8) | ((256 - kw) & 255);
  float rho1 = r1p[0], rho2 = r2p[0];
  cplx A  = X1F[(b << 16) | k];
  cplx Am = X1F[(b << 16) | k2];
  float hfr = 0.f, hfi = 0.f;
  #pragma unroll 1
  for (int p = 0; p < 16; ++p) {
    int pb = (b*16 + p) << 16;
    cplx Pk = P[pb | k], Pm = P[pb | k2];
    float Zr[2], Zi[2];
    Zr[0] = 0.5f*(Pk.x + Pm.x); Zi[0] = 0.5f*(Pk.y - Pm.y);
    Zr[1] = 0.5f*(Pk.y + Pm.y); Zi[1] = 0.5f*(Pm.x - Pk.x);
    float Xr[2], Xi[2];
    #pragma unroll
    for (int dd = 0; dd < 2; ++dd) {
      int db = (b*32 + 2*p + dd) << 16;
      float or1 = otr[db | k],  oi1 = oti[db | k];
      float or2 = otr[db | k2], oi2 = oti[db | k2];
      float Gr = 0.5f*(A.x*or1 + A.y*oi1 + Am.x*or2 + Am.y*oi2);
      float Gi = 0.5f*(A.y*or1 - A.x*oi1 + Am.x*oi2 - Am.y*or2);
      float di = 0.5f*(1.f/(rho2 + rho1*(or1*or1 + oi1*oi1))
                     + 1.f/(rho2 + rho1*(or2*or2 + oi2*oi2)));
      float xr = (rho1*Gr + rho2*Zr[dd])*di;
      float xi = (rho1*Gi + rho2*Zi[dd])*di;
      Xr[dd] = xr; Xi[dd] = xi;
      hfr += xr*or1 - xi*oi1;
      hfi += xr*oi1 + xi*or1;
    }
    Q[pb | k] = {Xr[0] - Xi[1], Xi[0] + Xr[1]};
  }
  HF[(b << 16) | k] = {hfr, hfi};
}

// ---------------- Phi update -------------------------------------------------
__global__ __launch_bounds__(256) void k_bisect(const float* __restrict__ holo,
                                                const float* __restrict__ minmax,
                                                const float* __restrict__ u1,
                                                const int* __restrict__ K1,
                                                const float* __restrict__ r1p,
                                                float* __restrict__ phi_out,
                                                float* __restrict__ u1_out) {
  int i = blockIdx.x*256 + threadIdx.x;
  int b = i >> 16;
  float mn = minmax[2*b], mx = minmax[2*b + 1];
  float fp = (holo[i] - mn) / (mx - mn);
  float pt = fp + u1[i];
  float K1f = (float)K1[i];
  float K0 = 1.f - K1f;
  float rho1 = r1p[0];
  bool ind0i = (K1f == 0.f);
  bool ind0 = ind0i;
  float pmin = 1e-5f, pmax = 100.f, pave = 0.5f*(pmin + pmax);
  #pragma unroll 1
  for (int it = 0; it < 30; ++it) {
    float e = expf(pave);
    float t = (K0 - K1f/(e - 1.f)) + rho1*(pave - pt);
    bool ind1 = !ind0;
    if (t > 0.f && ind1) pmin = pave;
    if (t < 0.f && ind1) pmax = pave;
    ind0 = ind0 || (t == 0.f && ind1);
    if (!ind0) pave = 0.5f*(pmin + pmax);
  }
  float pn = ind0i ? (pt - K0/rho1) : pave;
  phi_out[i] = pn;
  u1_out[i]  = u1[i] + pn - fp;
}

// =============================================================================
//                        Z-update: MFMA conv pipeline
// =============================================================================
__global__ __launch_bounds__(256) void k_wprep(const float* __restrict__ w1a,
                                               const float* __restrict__ w1b,
                                               const float* __restrict__ w2a,
                                               const float* __restrict__ w2b,
                                               unsigned short* __restrict__ Ap) {
  int idx = blockIdx.x*256 + threadIdx.x;
  if (idx >= 4*9216) return;
  int wsel = idx / 9216, r = idx - wsel*9216;
  const float* w = wsel==0 ? w1a : wsel==1 ? w1b : wsel==2 ? w2a : w2b;
  int tap = r / 1024, r2 = r - tap*1024, oc = r2 >> 5, ic = r2 & 31;
  Ap[idx] = f2bf(w[(oc*32 + ic)*9 + tap]);
}

__global__ __launch_bounds__(256) void k_cl0(const float* __restrict__ in,
                                             unsigned short* __restrict__ outCL) {
  __shared__ float t1[32*66];
  int tid = threadIdx.x;
  size_t b = blockIdx.y;
  int px0 = blockIdx.x * 64;
  #pragma unroll
  for (int i = 0; i < 2; ++i) {
    int ch = tid + i*256; int c = ch >> 4, p4 = (ch & 15)*4;
    float4 v = *(const float4*)(in + ((b*32 + c)<<16) + px0 + p4);
    t1[c*66 + p4] = v.x; t1[c*66+p4+1] = v.y; t1[c*66+p4+2] = v.z; t1[c*66+p4+3] = v.w;
  }
  __syncthreads();
  int px = tid >> 2, cg = tid & 3;
  unsigned short o[8];
  #pragma unroll
  for (int j = 0; j < 8; ++j) o[j] = f2bf(t1[(cg*8+j)*66 + px]);
  *(uint4*)(outCL + ((((b<<16) + px0 + px))<<5) + cg*8) = *(uint4*)o;
}

#define CONV_R 4
__global__ __launch_bounds__(256, 4) void k_conv(const unsigned short* __restrict__ inCL,
                                                 const unsigned short* __restrict__ Aprep,
                                                 unsigned short* __restrict__ outCL,
                                                 float* __restrict__ part,
                                                 int mode,
                                                 const float* __restrict__ scsh,
                                                 const float* __restrict__ thrp) {
  __shared__ unsigned short tile[6*66*32];
  __shared__ float sred[4][16][2];
  int tid = threadIdx.x;
  int bx = blockIdx.x, by = blockIdx.y, bz = blockIdx.z;
  int w0 = bx*64, h0 = by*CONV_R;
  float thr = (mode == 2) ? thrp[0] : 0.f;

  for (int idx = tid; idx < 6*264; idx += 256) {
    int lrow = idx/264, rem = idx - lrow*264;
    int lcol = rem >> 2, m = rem & 3;
    int grow = h0 - 1 + lrow, gcol = w0 - 1 + lcol;
    uint4 val = {0,0,0,0};
    if (grow >= 0 && grow < 256 && gcol >= 0 && gcol < 256) {
      uint4 raw = *(const uint4*)(inCL + (((size_t)(bz<<16) + (grow<<8) + gcol)<<5) + m*8);
      if (mode == 0) val = raw;
      else {
        unsigned short h8[8]; *(uint4*)h8 = raw;
        #pragma unroll
        for (int j = 0; j < 8; ++j) {
          float v = bf2f(h8[j]);
          if (mode == 1) { int ic = m*8+j; v = v*scsh[ic] + scsh[32+ic]; v = v > 0.f ? v : 0.01f*v; }
          else { float s = fabsf(v) - thr; s = s > 0.f ? s : 0.f; v = copysignf(s, v); }
          h8[j] = f2bf(v);
        }
        val = *(uint4*)h8;
      }
    }
    *(uint4*)&tile[(size_t)idx*8] = val;
  }

  int lane = tid & 63, w = tid >> 6;
  int q = lane >> 4, ln = lane & 15;
  int ocH = w & 1, s0 = w >> 1;
  short8 afrag[9];
  #pragma unroll
  for (int t = 0; t < 9; ++t)
    afrag[t] = *(const short8*)(Aprep + ((t*32 + ocH*16 + ln)*32 + q*8));
  __syncthreads();

  float sacc[4] = {0,0,0,0}, s2acc[4] = {0,0,0,0};
  #pragma unroll
  for (int r = 0; r < CONV_R; ++r) {
    #pragma unroll
    for (int si = 0; si < 2; ++si) {
      int s = s0 + si*2;
      float4v acc = {0.f, 0.f, 0.f, 0.f};
      #pragma unroll
      for (int t = 0; t < 9; ++t) {
        int dy = t/3, dx = t - dy*3;
        int lrow = r + dy, lcol = s*16 + ln + dx;
        const short8 bfrag = *(const short8*)&tile[(lrow*66 + lcol)*32 + q*8];
        acc = __builtin_amdgcn_mfma_f32_16x16x32_bf16(afrag[t], bfrag, acc, 0, 0, 0);
      }
      int px = w0 + s*16 + ln, row = h0 + r;
      size_t obase = ((((size_t)(bz<<16) + (row<<8) + px))<<5) + ocH*16 + q*4;
      unsigned short o4[4];
      #pragma unroll
      for (int u = 0; u < 4; ++u) { o4[u] = f2bf(acc[u]); sacc[u] += acc[u]; s2acc[u] += acc[u]*acc[u]; }
      *(uint2*)(outCL + obase) = *(uint2*)o4;
    }
  }

  #pragma unroll
  for (int u = 0; u < 4; ++u) {
    float a = sacc[u], b2 = s2acc[u];
    #pragma unroll
    for (int mq = 1; mq < 16; mq <<= 1) { a += __shfl_xor(a, mq); b2 += __shfl_xor(b2, mq); }
    if (ln == 0) { sred[w][q*4+u][0] = a; sred[w][q*4+u][1] = b2; }
  }
  __syncthreads();
  if (tid < 64) {
    int ocH2 = tid >> 5, i16 = (tid >> 1) & 15, st = tid & 1;
    float tot = sred[ocH2][i16][st] + sred[ocH2+2][i16][st];
    int oc = ocH2*16 + i16;
    int blk = ((bz<<6) + by)*4 + bx;
    part[(oc*2+st)*1024 + blk] = tot;
  }
}

__global__ __launch_bounds__(256) void k_finstats2(const float* __restrict__ part,
                                                   const float* __restrict__ g,
                                                   const float* __restrict__ beta,
                                                   float* __restrict__ SS) {
  __shared__ float red[64];
  int t = threadIdx.x, p = t >> 2, ch = t & 3;
  const float4* pp = (const float4*)(part + p*1024 + ch*256);
  float s = 0.f;
  for (int i = 0; i < 64; ++i) { float4 v = pp[i]; s += v.x + v.y + v.z + v.w; }
  s += __shfl_xor(s, 1); s += __shfl_xor(s, 2);
  if (ch == 0) red[p] = s;
  __syncthreads();
  if (t < 32) {
    const float N = 262144.f;
    float mean = red[t*2] / N;
    float var  = red[t*2+1] / N - mean*mean;
    float sc = g[t] * rsqrtf(var + 1e-5f);
    SS[t] = sc; SS[32+t] = beta[t] - mean*sc;
  }
}

__global__ __launch_bounds__(256) void k_h1cl(const unsigned short* __restrict__ zt,
                                              const unsigned short* __restrict__ c2,
                                              const float* __restrict__ SS,
                                              unsigned short* __restrict__ h1) {
  int idx = blockIdx.x*256 + threadIdx.x;
  int cg = idx & 3;
  uint4 za = *(const uint4*)(zt + (size_t)idx*8);
  uint4 ca = *(const uint4*)(c2 + (size_t)idx*8);
  unsigned short zs[8], cs[8], os[8];
  *(uint4*)zs = za; *(uint4*)cs = ca;
  #pragma unroll
  for (int j = 0; j < 8; ++j) {
    int c = cg*8 + j;
    float v = bf2f(zs[j]) + bf2f(cs[j])*SS[c] + SS[32+c];
    v = v > 0.f ? v : 0.01f*v;
    os[j] = f2bf(v);
  }
  *(uint4*)(h1 + (size_t)idx*8) = *(uint4*)os;
}

// fused finals: z, u2_next, sym (planar fp32)
__global__ __launch_bounds__(256) void k_finalAB(const unsigned short* __restrict__ h1,
                                                 const unsigned short* __restrict__ c4,
                                                 const unsigned short* __restrict__ c6,
                                                 const unsigned short* __restrict__ ztcl,
                                                 const float* __restrict__ SS4,
                                                 const float* __restrict__ SS6,
                                                 const float* __restrict__ thrp,
                                                 const float* __restrict__ u2,
                                                 const float* __restrict__ x,
                                                 float* __restrict__ zout,
                                                 float* __restrict__ u2out,
                                                 float* __restrict__ symout) {
  __shared__ float zT[32*66];
  __shared__ float sT[32*66];
  int tid = threadIdx.x;
  size_t b = blockIdx.y;
  int px0 = blockIdx.x*64;
  float thr = thrp[0];
  int px = tid >> 2, cg = tid & 3;
  size_t cbase = ((((b<<16) + px0 + px))<<5) + cg*8;
  uint4 ha = *(const uint4*)(h1 + cbase);
  uint4 c4a = *(const uint4*)(c4 + cbase);
  uint4 c6a = *(const uint4*)(c6 + cbase);
  uint4 za = *(const uint4*)(ztcl + cbase);
  unsigned short hs[8], c4s[8], c6s[8], zs[8];
  *(uint4*)hs = ha; *(uint4*)c4s = c4a; *(uint4*)c6s = c6a; *(uint4*)zs = za;
  #pragma unroll
  for (int j = 0; j < 8; ++j) {
    int c = cg*8+j;
    float hv = bf2f(hs[j]);
    float s = fabsf(hv) - thr; s = s > 0.f ? s : 0.f;
    float th = copysignf(s, hv);
    float zv = th + bf2f(c4s[j])*SS4[c] + SS4[32+c];
    zT[c*66 + px] = zv > 0.f ? zv : 0.01f*zv;
    float xv = hv + bf2f(c6s[j])*SS6[c] + SS6[32+c];
    xv = xv > 0.f ? xv : 0.01f*xv;
    sT[c*66 + px] = xv - bf2f(zs[j]);
  }
  __syncthreads();
  #pragma unroll
  for (int i = 0; i < 2; ++i) {
    int ch = tid + i*256; int c = ch >> 4, p4 = (ch & 15)*4;
    size_t g = ((b*32 + c)<<16) + px0 + p4;
    float4 uv = *(const float4*)(u2 + g);
    float4 xv = *(const float4*)(x + g);
    float4 zv = { zT[c*66+p4], zT[c*66+p4+1], zT[c*66+p4+2], zT[c*66+p4+3] };
    float4 un = { uv.x+zv.x-xv.x, uv.y+zv.y-xv.y, uv.z+zv.z-xv.z, uv.w+zv.w-xv.w };
    float4 sv = { sT[c*66+p4], sT[c*66+p4+1], sT[c*66+p4+2], sT[c*66+p4+3] };
    *(float4*)(zout + g) = zv;
    *(float4*)(u2out + g) = un;
    *(float4*)(symout + g) = sv;
  }
}

// ================================================================================
extern "C" void kernel_launch(void* const* d_in, const int* in_sizes, int n_in,
                              void* d_out, int out_size, void* d_ws, size_t ws_size,
                              hipStream_t stream) {
  const float* phi  = (const float*)d_in[1];
  const float* z    = (const float*)d_in[2];
  const float* u1   = (const float*)d_in[3];
  const float* u2   = (const float*)d_in[4];
  const float* otr  = (const float*)d_in[5];
  const float* oti  = (const float*)d_in[6];
  const int*   K1   = (const int*)d_in[7];
  const float* rho1 = (const float*)d_in[8];
  const float* rho2 = (const float*)d_in[9];
  const float* sthr = (const float*)d_in[10];
  const float* w1a = (const float*)d_in[11];
  const float* g1a = (const float*)d_in[12];
  const float* b1a = (const float*)d_in[13];
  const float* w1b = (const float*)d_in[14];
  const float* g1b = (const float*)d_in[15];
  const float* b1b = (const float*)d_in[16];
  const float* w2a = (const float*)d_in[17];
  const float* g2a = (const float*)d_in[18];
  const float* b2a = (const float*)d_in[19];
  const float* w2b = (const float*)d_in[20];
  const float* g2b = (const float*)d_in[21];
  const float* b2b = (const float*)d_in[22];

  float* out = (float*)d_out;
  float* x_out   = out;                 // [B,D,H,W]
  float* phi_out = out + 8388608;
  float* z_out   = out + 8650752;
  float* u1_out  = out + 17039360;
  float* u2_out  = out + 17301504;
  float* sym_out = out + 25690112;

  char* ws = (char*)d_ws;
  cplx*  P     = (cplx*)ws;                          // 33.5 MB packed fwd spectrum
  cplx*  Q     = (cplx*)(ws + 33554432);             // 33.5 MB packed Xh spectrum
  cplx*  X1R   = (cplx*)(ws + 67108864);             // 2 MB: X1F, then HF-rows
  cplx*  HFT   = (cplx*)(ws + 69206016);             // 2 MB: HF
  float* holo  = (float*)(ws + 71303168);            // 1 MB
  float* partmm= (float*)(ws + 72351744);
  float* mm    = (float*)(ws + 72355840);
  float* ZT    = (float*)ws;                         // planar zt (over dead P)

  unsigned short* Ap    = (unsigned short*)(ws + 71303168);   // over dead holo
  float*          part  = (float*)(ws + 71434240);
  float*          SSb   = (float*)(ws + 71696384);
  unsigned short* ZTcl  = (unsigned short*)(ws + 33554432);   // over dead Q lo
  unsigned short* H1cl  = (unsigned short*)(ws + 50331648);   // over dead Q hi
  unsigned short* C4cl  = (unsigned short*)(ws + 0);          // over dead ZT lo
  unsigned short* C2cl  = (unsigned short*)(ws + 16777216);   // over dead ZT hi
  unsigned short* C6cl  = (unsigned short*)(ws + 16777216);   // over dead C2cl (after h1cl)
  unsigned short* C135  = (unsigned short*)z_out;             // scratch (dead pre-finalAB)
  cplx* W2 = (cplx*)z_out;                                    // packed inverse rows

  // ---- X update (Fourier domain, packed pairs) ----
  k_row_fwd_sub  <<<dim3(16, 4),  256, 0, stream>>>(phi, u1, X1R);
  k_col_fwd      <<<dim3(16, 4),  256, 0, stream>>>(X1R);
  k_row_fwd_sub_p<<<dim3(16, 64), 256, 0, stream>>>(z, u2, P);
  k_col_fwd      <<<dim3(16, 64), 256, 0, stream>>>(P);
  k_combine_hf   <<<1024, 256, 0, stream>>>(P, Q, X1R, otr, oti, rho1, rho2, HFT);
  // forward_proj: iFT(HF) -> |.| -> min/max
  k_row_inv      <<<dim3(16, 4),  256, 0, stream>>>(HFT, X1R);
  k_col_inv_abs  <<<dim3(16, 4),  256, 0, stream>>>(X1R, holo, partmm);
  k_mm_reduce    <<<1, 64, 0, stream>>>(partmm, mm);
  // x = iFT(Q) (packed), zt = x + u2
  k_row_inv      <<<dim3(16, 64), 256, 0, stream>>>(Q, W2);
  k_col_inv_xzt_p<<<dim3(16, 64), 256, 0, stream>>>(W2, u2, x_out, ZT);
  // ---- Phi update ----
  k_bisect<<<1024, 256, 0, stream>>>(holo, mm, u1, K1, rho1, phi_out, u1_out);

  // ---- Z update ----
  k_wprep<<<144, 256, 0, stream>>>(w1a, w1b, w2a, w2b, Ap);
  k_cl0<<<dim3(1024, 4), 256, 0, stream>>>(ZT, ZTcl);

  dim3 cg(4, 64, 4);
  k_conv<<<cg, 256, 0, stream>>>(ZTcl, Ap + 0,      C135, part, 0, SSb,       sthr);
  k_finstats2<<<1, 256, 0, stream>>>(part, g1a, b1a, SSb + 0);
  k_conv<<<cg, 256, 0, stream>>>(C135, Ap + 9216,   C2cl, part, 1, SSb + 0,   sthr);
  k_finstats2<<<1, 256, 0, stream>>>(part, g1b, b1b, SSb + 64);
  k_h1cl<<<4096, 256, 0, stream>>>(ZTcl, C2cl, SSb + 64, H1cl);

  k_conv<<<cg, 256, 0, stream>>>(H1cl, Ap + 18432,  C135, part, 2, SSb,       sthr);
  k_finstats2<<<1, 256, 0, stream>>>(part, g2a, b2a, SSb + 128);
  k_conv<<<cg, 256, 0, stream>>>(C135, Ap + 27648,  C4cl, part, 1, SSb + 128, sthr);
  k_finstats2<<<1, 256, 0, stream>>>(part, g2b, b2b, SSb + 192);

  k_conv<<<cg, 256, 0, stream>>>(H1cl, Ap + 18432,  C135, part, 0, SSb,       sthr);
  k_finstats2<<<1, 256, 0, stream>>>(part, g2a, b2a, SSb + 256);
  k_conv<<<cg, 256, 0, stream>>>(C135, Ap + 27648,  C6cl, part, 1, SSb + 256, sthr);
  k_finstats2<<<1, 256, 0, stream>>>(part, g2b, b2b, SSb + 320);

  k_finalAB<<<dim3(1024, 4), 256, 0, stream>>>(H1cl, C4cl, C6cl, ZTcl,
                                               SSb + 192, SSb + 320, sthr, u2, x_out,
                                               z_out, u2_out, sym_out);
}